// Round 1
// 106.379 us; speedup vs baseline: 1.0071x; 1.0071x over previous
//
#include <hip/hip_runtime.h>
#include <utility>

#define FIELD 39
#define TILE  13      // 3 tiles of 13 = 39
#define DIM   16
#define BATCH 8192

// flat pair index of (i,j), i<j
__host__ __device__ constexpr int pair_base(int i) {
    return i * (FIELD - 1) - i * (i - 1) / 2;
}
__host__ __device__ constexpr int widx(int i, int j) {
    return pair_base(i) + (j - i - 1);
}

// ---- load tile T: 13 indices then 13 gathers; all indices compile-time ----
// NOTE: int (not size_t) element index: idx*16+d < 2^24 -> 32-bit addressing path
template <int T, size_t... Ks>
__device__ __forceinline__ void load_tile(const int* __restrict__ rowIdx,
                                          const float* __restrict__ emb,
                                          int d, float (&e)[TILE],
                                          std::index_sequence<Ks...>) {
    int idx[TILE];
    ((idx[Ks] = rowIdx[T * TILE + (int)Ks]), ...);
    ((e[Ks] = emb[idx[Ks] * DIM + d]), ...);
}

// ---- off-diagonal block (A < B): all 13x13 pairs valid ----
template <int A, int B, int II, size_t... Js>
__device__ __forceinline__ float inner_off(const float (&eB)[TILE],
                                           const float* __restrict__ fw,
                                           std::index_sequence<Js...>) {
    float s = 0.f;
    // fw[constexpr]: wave-uniform -> batched s_load from constant cache
    ((s = fmaf(fw[widx(A * TILE + II, B * TILE + (int)Js)], eB[Js], s)), ...);
    return s;
}
template <int A, int B, size_t... Is>
__device__ __forceinline__ void block_off(const float (&eA)[TILE],
                                          const float (&eB)[TILE],
                                          const float* __restrict__ fw,
                                          float (&acc)[4],
                                          std::index_sequence<Is...>) {
    ((acc[Is & 3] = fmaf(eA[Is],
                         inner_off<A, B, (int)Is>(eB, fw, std::make_index_sequence<TILE>{}),
                         acc[Is & 3])),
     ...);
}

// ---- diagonal block: triangular ii < jj within the tile ----
template <int A, int II, size_t... Js>
__device__ __forceinline__ float inner_diag(const float (&e)[TILE],
                                            const float* __restrict__ fw,
                                            std::index_sequence<Js...>) {
    float s = 0.f;
    ((s = fmaf(fw[widx(A * TILE + II, A * TILE + II + 1 + (int)Js)],
               e[II + 1 + Js], s)),
     ...);
    return s;
}
template <int A, size_t... Is>
__device__ __forceinline__ void block_diag(const float (&e)[TILE],
                                           const float* __restrict__ fw,
                                           float (&acc)[4],
                                           std::index_sequence<Is...>) {
    ((acc[Is & 3] = fmaf(e[Is],
                         inner_diag<A, (int)Is>(e, fw,
                             std::make_index_sequence<TILE - 1 - Is>{}),
                         acc[Is & 3])),
     ...);
}

// 3-way pair split per row, one wave per split:
//   wave0: off(0,1) + diag(0)   tiles {0,1}, fo fields  0..12
//   wave1: off(1,2) + diag(1)   tiles {1,2}, fo fields 13..25
//   wave2: off(0,2) + diag(2)   tiles {0,2}, fo fields 26..38
// Block = 192 threads = 3 waves x (4 rows x 16 dims). Grid = BATCH/4 = 2048
// blocks -> ~24 waves/CU (vs 8 before). Each thread: 26 idx loads + 26 gathers
// + 1 lw gather, all independent, ONE wait point before ~290 FMAs.
__global__ __launch_bounds__(192, 6) void fwfm_kernel(
    const int*   __restrict__ inputs,   // [BATCH][FIELD]
    const float* __restrict__ emb,      // [1M][DIM]
    const float* __restrict__ fw,       // [741]
    const float* __restrict__ lw,       // [1M]
    const float* __restrict__ bias,     // [1]
    float*       __restrict__ out)      // [BATCH]
{
    const int tid  = threadIdx.x;
    const int lane = tid & 63;
    const int wave = tid >> 6;        // 0..2, wave-uniform
    const int d    = lane & 15;       // dim owned by this lane
    const int rloc = lane >> 4;       // row within wave (0..3)
    const int row  = blockIdx.x * 4 + rloc;

    const int* rowIdx = inputs + row * FIELD;

    float eA[TILE], eB[TILE];
    float acc[4] = {0.f, 0.f, 0.f, 0.f};
    float fo = 0.f;
    const auto seqT = std::make_index_sequence<TILE>{};

    if (wave == 0) {
        load_tile<0>(rowIdx, emb, d, eA, seqT);
        load_tile<1>(rowIdx, emb, d, eB, seqT);
        if (d < TILE) fo = lw[rowIdx[d]];
        block_off<0, 1>(eA, eB, fw, acc, seqT);
        block_diag<0>(eA, fw, acc, seqT);
    } else if (wave == 1) {
        load_tile<1>(rowIdx, emb, d, eA, seqT);
        load_tile<2>(rowIdx, emb, d, eB, seqT);
        if (d < TILE) fo = lw[rowIdx[TILE + d]];
        block_off<1, 2>(eA, eB, fw, acc, seqT);
        block_diag<1>(eA, fw, acc, seqT);
    } else {
        load_tile<0>(rowIdx, emb, d, eA, seqT);
        load_tile<2>(rowIdx, emb, d, eB, seqT);
        if (d < TILE) fo = lw[rowIdx[2 * TILE + d]];
        block_off<0, 2>(eA, eB, fw, acc, seqT);
        block_diag<2>(eB, fw, acc, seqT);
    }

    // ---- reduce the 16 dim-lanes of this (row, wave-partition) ----
    float tot = fo + (acc[0] + acc[1]) + (acc[2] + acc[3]);
    tot += __shfl_xor(tot, 1, 64);
    tot += __shfl_xor(tot, 2, 64);
    tot += __shfl_xor(tot, 4, 64);
    tot += __shfl_xor(tot, 8, 64);

    // ---- combine the 3 wave-partitions via 48 B of LDS ----
    __shared__ float part[3][4];
    if (d == 0) part[wave][rloc] = tot;
    __syncthreads();
    if (tid < 4) {
        out[blockIdx.x * 4 + tid] =
            part[0][tid] + part[1][tid] + part[2][tid] + bias[0];
    }
}

extern "C" void kernel_launch(void* const* d_in, const int* in_sizes, int n_in,
                              void* d_out, int out_size, void* d_ws, size_t ws_size,
                              hipStream_t stream) {
    const int*   inputs = (const int*)  d_in[0];
    const float* emb    = (const float*)d_in[1];
    const float* fw     = (const float*)d_in[2];
    const float* lw     = (const float*)d_in[3];
    const float* bias   = (const float*)d_in[4];
    float*       out    = (float*)      d_out;

    dim3 grid(BATCH / 4);   // 2048 blocks * 3 waves * 4 rows = 8192 rows
    fwfm_kernel<<<grid, 192, 0, stream>>>(inputs, emb, fw, lw, bias, out);
}